// Round 1
// 707.557 us; speedup vs baseline: 1.2423x; 1.2423x over previous
//
#include <hip/hip_runtime.h>

typedef unsigned short u16;
typedef __bf16 bf16x8 __attribute__((ext_vector_type(8)));
typedef float f32x4 __attribute__((ext_vector_type(4)));

#define AS1 __attribute__((address_space(1)))
#define AS3 __attribute__((address_space(3)))
#define MFMA(a,b,c) __builtin_amdgcn_mfma_f32_16x16x32_bf16(a,b,c,0,0,0)

__device__ __forceinline__ u16 f2bf(float f) {
    union { float f; unsigned u; } x; x.f = f;
    unsigned r = x.u + 0x7fffu + ((x.u >> 16) & 1u);
    return (u16)(r >> 16);
}

// ---------------- patch_w -> bf16, transposed AND K-permuted ----------------
// out[n][k'] with k' = c*256 + p1*16 + p2 ; in patch_w[k=p1*2048+p2*128+c][n]
// grid (128 c, 16 n-tiles), 256 threads
__global__ void k_patch_wT(const float* __restrict__ w, u16* __restrict__ o)
{
    __shared__ u16 T[256*33];
    int c = blockIdx.x, n0 = blockIdx.y*32;
    int t = threadIdx.x;
    int rr = t >> 5, cc = t & 31;
    #pragma unroll
    for (int i = 0; i < 32; ++i) {
        int r = i*8 + rr;                       // r = p1*16 + p2
        int k = (r >> 4)*2048 + (r & 15)*128 + c;
        T[r*33 + cc] = f2bf(w[(size_t)k*512 + n0 + cc]);
    }
    __syncthreads();
    #pragma unroll
    for (int i = 0; i < 4; ++i) {
        int j  = i*8 + (t >> 5);                // n row 0..31
        int ch = t & 31;                        // uint4 chunk: r = ch*8..ch*8+7
        union { u16 u[8]; uint4 v; } pk;
        #pragma unroll
        for (int q = 0; q < 8; ++q) pk.u[q] = T[(ch*8+q)*33 + j];
        *(uint4*)(o + (size_t)(n0 + j)*32768 + c*256 + ch*8) = pk.v;
    }
}

// ---------------- x init: patch_b + pos_emb ----------------
__global__ void k_init_x(float* __restrict__ x, const float* __restrict__ pb, const float* __restrict__ pe)
{
    int i4 = blockIdx.x*256 + threadIdx.x;
    size_t base = (size_t)i4*4;
    float4 a = *(const float4*)(pb + (base & 511));
    float4 b = *(const float4*)(pe + (base & 524287));
    float4 r = make_float4(a.x+b.x, a.y+b.y, a.z+b.z, a.w+b.w);
    *(float4*)(x + base) = r;
}

// ---------------- fused patch-embed GEMM: img (rearranged on the fly) @ pwT' ----------------
// M=4096 tokens, N=512 (full width per block), K=32768 split 8 ways (16 c each).
// grid 256 blocks: z = bid%8 (-> one z per XCD, B-slice L2-resident), m-tile = bid/8.
// 1024 threads = 16 waves as 2(m)x8(n), wave tile 64x64. LDS double-buffered (160 KiB).
__global__ __launch_bounds__(1024) void k_patch_gemm(
    const float* __restrict__ img, const u16* __restrict__ Bt, float* __restrict__ Cf)
{
    __shared__ alignas(16) u16 As[2*128*64];   //  32 KiB
    __shared__ alignas(16) u16 Bs[2*512*64];   // 128 KiB
    const int t = threadIdx.x;
    const int bid = blockIdx.x;
    const int z = bid & 7;                     // K-split: c in [z*16, z*16+16)
    const int tile = bid >> 3;                 // m-tile [0,32)
    const int b = tile >> 3, gh0 = (tile & 7)*4;
    const int m0 = tile*128;
    const int wave = t >> 6, lane = t & 63;
    const int r16 = lane & 15, g = lane >> 4;
    const int wm = (wave >> 3)*64, wn = (wave & 7)*64;

    // A staging geometry: wave w loads img row w (16 rows of 512 floats per chunk)
    const int arow = t >> 6;                   // [0,16): ghl*4 + p1l
    const int ghl = arow >> 2, p1l = arow & 3;
    const int aw = (t & 63)*8;                 // [0,512) step 8 floats
    const int tok = ghl*32 + (aw >> 4);        // local token [0,128)
    unsigned abyte = (unsigned)(tok*128 + p1l*32 + (aw & 15)*2);
    abyte ^= (unsigned)((tok & 7) << 4);       // XOR-swizzle (write side)
    const float* imgb = img + (size_t)b*128*262144
                      + (size_t)((gh0 + ghl)*16 + p1l)*512 + aw;
    // B staging: pre-swizzled per-lane global source so linear LDS dest lands swizzled
    const int brow = t >> 3;                   // [0,128)
    const int bchunk = (t & 7) ^ (brow & 7);
    const u16* Bb = Bt + (size_t)brow*32768 + (size_t)z*4096 + bchunk*8;
    u16* Bsd = Bs + t*8;

    f32x4 acc[4][4];
    const f32x4 zz = {0.f,0.f,0.f,0.f};
    #pragma unroll
    for (int im = 0; im < 4; ++im)
        #pragma unroll
        for (int in_ = 0; in_ < 4; ++in_) acc[im][in_] = zz;

#define STAGE(KC, BUF) do {                                                          \
    const int c_ = z*16 + ((KC) >> 2);                                               \
    const float* src_ = imgb + (size_t)c_*262144 + ((KC) & 3)*2048;                  \
    float4 a0_ = *(const float4*)src_;                                               \
    float4 a1_ = *(const float4*)(src_ + 4);                                         \
    _Pragma("unroll")                                                                \
    for (int i_ = 0; i_ < 4; ++i_)                                                   \
        __builtin_amdgcn_global_load_lds((AS1 void*)(Bb + (size_t)i_*128*32768 + (KC)*64), \
                                         (AS3 void*)(Bsd + (BUF)*32768 + i_*8192), 16, 0, 0); \
    union { u16 u[8]; uint4 v; } pk_;                                                \
    pk_.u[0]=f2bf(a0_.x); pk_.u[1]=f2bf(a0_.y); pk_.u[2]=f2bf(a0_.z); pk_.u[3]=f2bf(a0_.w); \
    pk_.u[4]=f2bf(a1_.x); pk_.u[5]=f2bf(a1_.y); pk_.u[6]=f2bf(a1_.z); pk_.u[7]=f2bf(a1_.w); \
    *(uint4*)((char*)As + (BUF)*16384 + abyte) = pk_.v;                              \
} while(0)

    STAGE(0, 0);
    __syncthreads();
    int cur = 0;
    for (int kc = 0; kc < 64; ++kc) {
        if (kc < 63) STAGE(kc + 1, cur ^ 1);
        const char* Asb = (const char*)As + cur*16384;
        const char* Bsb = (const char*)Bs + cur*65536;
        #pragma unroll
        for (int kk = 0; kk < 64; kk += 32) {
            bf16x8 af[4], bfr[4];
            #pragma unroll
            for (int im = 0; im < 4; ++im) {
                unsigned off = ((unsigned)((wm + im*16 + r16)*128 + kk*2 + g*16))
                             ^ (unsigned)((r16 & 7) << 4);
                af[im] = *(const bf16x8*)(Asb + off);
            }
            #pragma unroll
            for (int in_ = 0; in_ < 4; ++in_) {
                unsigned off = ((unsigned)((wn + in_*16 + r16)*128 + kk*2 + g*16))
                             ^ (unsigned)((r16 & 7) << 4);
                bfr[in_] = *(const bf16x8*)(Bsb + off);
            }
            #pragma unroll
            for (int im = 0; im < 4; ++im)
                #pragma unroll
                for (int in_ = 0; in_ < 4; ++in_)
                    acc[im][in_] = MFMA(af[im], bfr[in_], acc[im][in_]);
        }
        __syncthreads();
        cur ^= 1;
    }
#undef STAGE
    #pragma unroll
    for (int im = 0; im < 4; ++im) {
        int row = m0 + wm + im*16 + g*4;
        #pragma unroll
        for (int in_ = 0; in_ < 4; ++in_) {
            int col = wn + in_*16 + r16;
            #pragma unroll
            for (int r = 0; r < 4; ++r)
                __hip_atomic_fetch_add(&Cf[(size_t)(row + r)*512 + col], acc[im][in_][r],
                                       __ATOMIC_RELAXED, __HIP_MEMORY_SCOPE_AGENT);
        }
    }
}

// ---------------- transpose + fp32->bf16: in[K][N] -> out[N][K] ----------------
__global__ void k_transpose_cvt(const float* __restrict__ in, u16* __restrict__ o, int K, int N)
{
    __shared__ float T[32*33];
    int kt = blockIdx.x*32, nt = blockIdx.y*32;
    int t = threadIdx.x, r = t >> 5, c = t & 31;
    #pragma unroll
    for (int i = 0; i < 4; ++i)
        T[(r + i*8)*33 + c] = in[(size_t)(kt + r + i*8)*N + nt + c];
    __syncthreads();
    #pragma unroll
    for (int i = 0; i < 4; ++i)
        o[(size_t)(nt + r + i*8)*K + kt + c] = f2bf(T[c*33 + r + i*8]);
}

// ---------------- LayerNorm: one wave per 512-wide row, fp32 in -> bf16 out ----------------
__global__ void k_ln(const float* __restrict__ x, const float* __restrict__ sc,
                     const float* __restrict__ bi, u16* __restrict__ o)
{
    int row = blockIdx.x, lane = threadIdx.x;
    const float* xr = x + (size_t)row*512 + lane*8;
    float4 v0 = *(const float4*)xr;
    float4 v1 = *(const float4*)(xr + 4);
    float vv[8] = {v0.x,v0.y,v0.z,v0.w,v1.x,v1.y,v1.z,v1.w};
    float sum = 0.f, sq = 0.f;
    #pragma unroll
    for (int i = 0; i < 8; ++i) { sum += vv[i]; sq += vv[i]*vv[i]; }
    #pragma unroll
    for (int m = 1; m < 64; m <<= 1) { sum += __shfl_xor(sum, m, 64); sq += __shfl_xor(sq, m, 64); }
    float mean = sum * (1.f/512.f);
    float var  = sq  * (1.f/512.f) - mean*mean;
    float rstd = rsqrtf(var + 1e-5f);
    int d = lane*8;
    union { u16 u[8]; uint4 v; } pk;
    #pragma unroll
    for (int i = 0; i < 8; ++i) pk.u[i] = f2bf((vv[i]-mean)*rstd*sc[d+i] + bi[d+i]);
    *(uint4*)(o + (size_t)row*512 + d) = pk.v;
}

// ---------------- generic bf16 GEMM: A[M][K] @ Bt[N][K]^T, 128x128x64 tiles ----------------
// EPI: 1 = bf16 store, 2 = gelu(acc+bias) bf16, 3 = Cf += acc+bias
template<int EPI>
__global__ __launch_bounds__(256) void k_gemm(
    const u16* __restrict__ A, int lda,
    const u16* __restrict__ Bt, int ldb,
    int Kblk,
    float* __restrict__ Cf, u16* __restrict__ Cb, int ldc,
    const float* __restrict__ bias)
{
    __shared__ alignas(16) u16 As[128*64];
    __shared__ alignas(16) u16 Bs[128*64];
    const int t = threadIdx.x;
    const int m0 = blockIdx.x*128, n0 = blockIdx.y*128;
    const int kz = blockIdx.z*Kblk;
    const int wave = t >> 6, lane = t & 63;
    const int wm = (wave >> 1)*64, wn = (wave & 1)*64;
    const int r16 = lane & 15, g = lane >> 4;
    const u16* Ab = A + (size_t)(m0 + (t>>3))*lda + kz + (t&7)*8;
    const u16* Bb = Bt + (size_t)(n0 + (t>>3))*ldb + kz + (t&7)*8;
    u16* Asd = As + t*8;
    u16* Bsd = Bs + t*8;
    f32x4 acc[4][4];
    const f32x4 z4 = {0.f,0.f,0.f,0.f};
    #pragma unroll
    for (int im = 0; im < 4; ++im)
        #pragma unroll
        for (int in_ = 0; in_ < 4; ++in_) acc[im][in_] = z4;

    for (int k = 0; k < Kblk; k += 64) {
        #pragma unroll
        for (int i = 0; i < 4; ++i) {
            __builtin_amdgcn_global_load_lds((AS1 void*)(Ab + (size_t)i*32*lda + k), (AS3 void*)(Asd + i*2048), 16, 0, 0);
            __builtin_amdgcn_global_load_lds((AS1 void*)(Bb + (size_t)i*32*ldb + k), (AS3 void*)(Bsd + i*2048), 16, 0, 0);
        }
        __syncthreads();
        #pragma unroll
        for (int kk = 0; kk < 64; kk += 32) {
            bf16x8 af[4], bfr[4];
            #pragma unroll
            for (int im = 0; im < 4; ++im)
                af[im] = *(const bf16x8*)(As + (wm + im*16 + r16)*64 + kk + g*8);
            #pragma unroll
            for (int in_ = 0; in_ < 4; ++in_)
                bfr[in_] = *(const bf16x8*)(Bs + (wn + in_*16 + r16)*64 + kk + g*8);
            #pragma unroll
            for (int im = 0; im < 4; ++im)
                #pragma unroll
                for (int in_ = 0; in_ < 4; ++in_)
                    acc[im][in_] = MFMA(af[im], bfr[in_], acc[im][in_]);
        }
        __syncthreads();
    }
    #pragma unroll
    for (int im = 0; im < 4; ++im) {
        int row = m0 + wm + im*16 + g*4;
        #pragma unroll
        for (int in_ = 0; in_ < 4; ++in_) {
            int col = n0 + wn + in_*16 + r16;
            #pragma unroll
            for (int r = 0; r < 4; ++r) {
                float v = acc[im][in_][r];
                size_t idx = (size_t)(row + r)*ldc + col;
                if constexpr (EPI == 1) {
                    Cb[idx] = f2bf(v);
                } else if constexpr (EPI == 2) {
                    float xv = v + bias[col];
                    Cb[idx] = f2bf(0.5f*xv*(1.f + erff(xv*0.70710678118654752f)));
                } else {
                    Cf[idx] += v + bias[col];
                }
            }
        }
    }
}

// ---------------- flash attention with relative position bias ----------------
// grid: (16 q-tiles, H heads, 4 batch); block 256 = 4 waves x 16 q-rows each
__global__ __launch_bounds__(256) void k_attn(
    const u16* __restrict__ qkv, const float* __restrict__ bt,
    u16* __restrict__ o, int H)
{
    const int LD = 80;
    __shared__ alignas(16) u16 Qs[64*80], Ks[64*80], Vs[64*80];
    __shared__ alignas(16) u16 Ps[4][16*80];
    const int inner = H*64, s3 = 3*inner;
    const int qt = blockIdx.x, head = blockIdx.y, b = blockIdx.z;
    const int t = threadIdx.x, wave = t >> 6, lane = t & 63;
    const int r16 = lane & 15, g = lane >> 4;
    const int q0 = qt*64;
    const size_t tokbase = (size_t)b*1024;
    const int hoff = head*64;

    #pragma unroll
    for (int it = 0; it < 2; ++it) {
        int flat = it*256 + t, r = flat >> 3, d0 = (flat & 7)*8;
        uint4 v = *(const uint4*)(qkv + (tokbase + q0 + r)*s3 + hoff + d0);
        *(uint4*)(Qs + r*LD + d0) = v;
    }
    __syncthreads();
    bf16x8 aQ0 = *(const bf16x8*)(Qs + (wave*16 + r16)*LD + g*8);
    bf16x8 aQ1 = *(const bf16x8*)(Qs + (wave*16 + r16)*LD + 32 + g*8);

    float m_[4], l_[4];
    f32x4 O[4];
    const f32x4 z4 = {0.f,0.f,0.f,0.f};
    #pragma unroll
    for (int r = 0; r < 4; ++r) { m_[r] = -1e30f; l_[r] = 0.f; O[r] = z4; }
    const int qg_base = q0 + wave*16 + g*4;

    for (int kt = 0; kt < 16; ++kt) {
        const int key0 = kt*64;
        #pragma unroll
        for (int it = 0; it < 2; ++it) {
            int flat = it*256 + t, r = flat >> 3, d0 = (flat & 7)*8;
            uint4 v = *(const uint4*)(qkv + (tokbase + key0 + r)*s3 + inner + hoff + d0);
            *(uint4*)(Ks + r*LD + d0) = v;
        }
        #pragma unroll
        for (int it = 0; it < 2; ++it) {
            int flat = it*256 + t, key = flat & 63, d0 = (flat >> 6)*8;
            uint4 v = *(const uint4*)(qkv + (tokbase + key0 + key)*s3 + 2*inner + hoff + d0);
            const u16* pv = (const u16*)&v;
            #pragma unroll
            for (int i = 0; i < 8; ++i) Vs[(d0+i)*LD + key] = pv[i];
        }
        __syncthreads();

        float Sv[4][4];
        #pragma unroll
        for (int kb = 0; kb < 4; ++kb) {
            bf16x8 k0f = *(const bf16x8*)(Ks + (kb*16 + r16)*LD + g*8);
            bf16x8 k1f = *(const bf16x8*)(Ks + (kb*16 + r16)*LD + 32 + g*8);
            f32x4 S = z4;
            S = MFMA(aQ0, k0f, S);
            S = MFMA(aQ1, k1f, S);
            int keyg = key0 + kb*16 + r16;
            int kgh = keyg >> 5, kgw = keyg & 31;
            #pragma unroll
            for (int r = 0; r < 4; ++r) {
                int qg = qg_base + r;
                int rel = ((qg >> 5) - kgh + 31)*63 + ((qg & 31) - kgw + 31);
                Sv[kb][r] = S[r]*0.125f + bt[rel*H + head];
            }
        }
        float mx[4], al[4], ps[4];
        #pragma unroll
        for (int r = 0; r < 4; ++r)
            mx[r] = fmaxf(fmaxf(Sv[0][r], Sv[1][r]), fmaxf(Sv[2][r], Sv[3][r]));
        #pragma unroll
        for (int msk = 1; msk < 16; msk <<= 1)
            #pragma unroll
            for (int r = 0; r < 4; ++r) mx[r] = fmaxf(mx[r], __shfl_xor(mx[r], msk, 64));
        #pragma unroll
        for (int r = 0; r < 4; ++r) {
            float nm = fmaxf(m_[r], mx[r]);
            al[r] = __expf(m_[r] - nm);
            m_[r] = nm;
            ps[r] = 0.f;
        }
        #pragma unroll
        for (int kb = 0; kb < 4; ++kb)
            #pragma unroll
            for (int r = 0; r < 4; ++r) {
                float p = __expf(Sv[kb][r] - m_[r]);
                Sv[kb][r] = p;
                ps[r] += p;
            }
        #pragma unroll
        for (int msk = 1; msk < 16; msk <<= 1)
            #pragma unroll
            for (int r = 0; r < 4; ++r) ps[r] += __shfl_xor(ps[r], msk, 64);
        #pragma unroll
        for (int r = 0; r < 4; ++r) l_[r] = l_[r]*al[r] + ps[r];
        #pragma unroll
        for (int kb = 0; kb < 4; ++kb)
            #pragma unroll
            for (int r = 0; r < 4; ++r)
                Ps[wave][(g*4 + r)*LD + kb*16 + r16] = f2bf(Sv[kb][r]);
        #pragma unroll
        for (int dt = 0; dt < 4; ++dt)
            #pragma unroll
            for (int r = 0; r < 4; ++r) O[dt][r] = O[dt][r]*al[r];
        __syncthreads();
        bf16x8 aP0 = *(const bf16x8*)(Ps[wave] + r16*LD + g*8);
        bf16x8 aP1 = *(const bf16x8*)(Ps[wave] + r16*LD + 32 + g*8);
        #pragma unroll
        for (int dt = 0; dt < 4; ++dt) {
            bf16x8 v0 = *(const bf16x8*)(Vs + (dt*16 + r16)*LD + g*8);
            bf16x8 v1 = *(const bf16x8*)(Vs + (dt*16 + r16)*LD + 32 + g*8);
            O[dt] = MFMA(aP0, v0, O[dt]);
            O[dt] = MFMA(aP1, v1, O[dt]);
        }
        __syncthreads();
    }
    #pragma unroll
    for (int dt = 0; dt < 4; ++dt)
        #pragma unroll
        for (int r = 0; r < 4; ++r) {
            int token = q0 + wave*16 + g*4 + r;
            o[(tokbase + token)*inner + hoff + dt*16 + r16] = f2bf(O[dt][r] / l_[r]);
        }
}

// ---------------- final: x[b][n][d] -> out[b][d][gh][gw] ----------------
__global__ void k_out_transpose(const float* __restrict__ x, float* __restrict__ o)
{
    __shared__ float T[32*33];
    int d0 = blockIdx.x*32, n0 = blockIdx.y*32, b = blockIdx.z;
    int t = threadIdx.x, r = t >> 5, c = t & 31;
    #pragma unroll
    for (int i = 0; i < 4; ++i)
        T[(r+i*8)*33 + c] = x[((size_t)b*1024 + n0 + r + i*8)*512 + d0 + c];
    __syncthreads();
    #pragma unroll
    for (int i = 0; i < 4; ++i)
        o[((size_t)b*512 + d0 + r + i*8)*1024 + n0 + c] = T[c*33 + (r+i*8)];
}

extern "C" void kernel_launch(void* const* d_in, const int* in_sizes, int n_in,
                              void* d_out, int out_size, void* d_ws, size_t ws_size,
                              hipStream_t stream)
{
    (void)in_sizes; (void)n_in; (void)out_size; (void)ws_size;
    const float* img     = (const float*)d_in[0];
    const float* patch_w = (const float*)d_in[1];
    const float* patch_b = (const float*)d_in[2];
    const float* pos_emb = (const float*)d_in[3];
    const float* ln1_s   = (const float*)d_in[4];
    const float* ln1_b   = (const float*)d_in[5];
    const float* ln2_s   = (const float*)d_in[6];
    const float* ln2_b   = (const float*)d_in[7];
    const float* qkv_w[3] = {(const float*)d_in[8],  (const float*)d_in[12], (const float*)d_in[16]};
    const float* out_w[3] = {(const float*)d_in[9],  (const float*)d_in[13], (const float*)d_in[17]};
    const float* out_b[3] = {(const float*)d_in[10], (const float*)d_in[14], (const float*)d_in[18]};
    const float* biasT[3] = {(const float*)d_in[11], (const float*)d_in[15], (const float*)d_in[19]};
    const float* ff_w1 = (const float*)d_in[20];
    const float* ff_b1 = (const float*)d_in[21];
    const float* ff_w2 = (const float*)d_in[22];
    const float* ff_b2 = (const float*)d_in[23];
    float* out = (float*)d_out;

    char* ws = (char*)d_ws;
    size_t off = 0;
    auto alloc = [&](size_t bytes) -> void* {
        void* p = ws + off; off += (bytes + 255) & ~(size_t)255; return p;
    };
    u16*   pwT  = (u16*)  alloc(512ull*32768*2);
    float* x    = (float*)alloc(4096ull*512*4);
    u16*   xn   = (u16*)  alloc(4096ull*512*2);
    u16*   qkv  = (u16*)  alloc(4096ull*1536*2);
    u16*   ob   = (u16*)  alloc(4096ull*512*2);
    u16*   mid  = (u16*)  alloc(4096ull*256*2);
    u16*   qkvT = (u16*)  alloc(1536ull*512*2);
    u16*   outT = (u16*)  alloc(512ull*512*2);
    u16*   f1T  = (u16*)  alloc(256ull*512*2);
    u16*   f2T  = (u16*)  alloc(512ull*256*2);

    // patch_w -> bf16 transposed + K-permuted to (c,p1,p2)
    k_patch_wT<<<dim3(128,16), 256, 0, stream>>>(patch_w, pwT);
    // x = patch_b + pos_emb
    k_init_x<<<2048, 256, 0, stream>>>(x, patch_b, pos_emb);
    // fused patch-embed GEMM straight from img (K-split 8, atomic fp32 accumulate)
    k_patch_gemm<<<256, 1024, 0, stream>>>(img, pwT, x);

    const int HS[3] = {2,4,8};
    for (int l = 0; l < 3; ++l) {
        int h = HS[l], inner = 64*h, n3 = 3*inner;
        k_transpose_cvt<<<dim3(16, n3/32),    256, 0, stream>>>(qkv_w[l], qkvT, 512, n3);
        k_transpose_cvt<<<dim3(inner/32, 16), 256, 0, stream>>>(out_w[l], outT, inner, 512);
        k_transpose_cvt<<<dim3(16, 8),        256, 0, stream>>>(ff_w1 + (size_t)l*512*256, f1T, 512, 256);
        k_transpose_cvt<<<dim3(8, 16),        256, 0, stream>>>(ff_w2 + (size_t)l*256*512, f2T, 256, 512);

        k_ln<<<4096, 64, 0, stream>>>(x, ln1_s + l*512, ln1_b + l*512, xn);
        k_gemm<1><<<dim3(32, n3/128), 256, 0, stream>>>(xn, 512, qkvT, 512, 512,
                                                        nullptr, qkv, n3, nullptr);
        k_attn<<<dim3(16, h, 4), 256, 0, stream>>>(qkv, biasT[l], ob, h);
        k_gemm<3><<<dim3(32, 4), 256, 0, stream>>>(ob, inner, outT, inner, inner,
                                                   x, nullptr, 512, out_b[l]);
        k_ln<<<4096, 64, 0, stream>>>(x, ln2_s + l*512, ln2_b + l*512, xn);
        k_gemm<2><<<dim3(32, 2), 256, 0, stream>>>(xn, 512, f1T, 512, 512,
                                                   nullptr, mid, 256, ff_b1 + l*256);
        k_gemm<3><<<dim3(32, 4), 256, 0, stream>>>(mid, 256, f2T, 256, 256,
                                                   x, nullptr, 512, ff_b2 + l*512);
    }
    k_out_transpose<<<dim3(16, 32, 4), 256, 0, stream>>>(x, out);
}